// Round 6
// baseline (280.643 us; speedup 1.0000x reference)
//
#include <hip/hip_runtime.h>

typedef float  float4v __attribute__((ext_vector_type(4)));
typedef int    int4v   __attribute__((ext_vector_type(4)));

// Defensive scalar read: Python scalars arrive as 1-element arrays whose dtype
// may be int32 or float32.
__device__ __forceinline__ float scalar_as_float(const void* p) {
    int iv = *(const int*)p;
    if (iv >= -1000000 && iv <= 1000000) return (float)iv;
    return *(const float*)p;
}
__device__ __forceinline__ int scalar_as_int(const void* p) {
    int iv = *(const int*)p;
    if (iv >= -1000000 && iv <= 1000000) return iv;
    return (int)(*(const float*)p);
}

__device__ __forceinline__ float bce4(float4v xv, int4v iv, int mid, float t) {
    float e[4];
    #pragma unroll
    for (int j = 0; j < 4; ++j) {
        float xx = xv[j];
        float w  = (iv[j] >= mid) ? 2.0f : 1.0f;
        float a  = fabsf(xx);
        // stable BCE-with-logits: max(x,0) - x*t + log(1 + exp(-|x|))
        float bce = fmaxf(xx, 0.0f) - xx * t + __logf(1.0f + __expf(-a));
        e[j] = w * bce;
    }
    return (e[0] + e[1]) + (e[2] + e[3]);
}

// Rounds 3/5 lesson: the allocator squeezed to 24-36 VGPR and re-serialized
// every source-level pipeline. Here the 8-load cluster is pinned by a
// sched_barrier(0) fence (compiler cannot sink loads across it), forcing all
// 8 results live -> real MLP. launch_bounds(256,4) allows up to 128 VGPR.
__global__ __launch_bounds__(256, 4) void rwl_partial_kernel(
        const float* __restrict__ x,
        const int*   __restrict__ idx,
        const void*  __restrict__ target_p,
        const void*  __restrict__ H_p,
        float* __restrict__ partials,
        int n_vec, int n_total, int n_super)
{
    const float t   = scalar_as_float(target_p);
    const int   mid = scalar_as_int(H_p) >> 1;

    const int lane = threadIdx.x & 63;
    const int wid  = threadIdx.x >> 6;
    const int gw   = blockIdx.x * (blockDim.x >> 6) + wid;   // global wave id
    const int GW   = gridDim.x * (blockDim.x >> 6);          // total waves

    const float4v* __restrict__ xv4 = (const float4v*)x;
    const int4v*   __restrict__ iv4 = (const int4v*)idx;

    float acc0 = 0.0f, acc1 = 0.0f, acc2 = 0.0f, acc3 = 0.0f;

    // Each wave handles 256 float4s per superstep: 4 x 1KB per stream at
    // lane-stride 64 (byte offsets +0/+1024/+2048/+3072 fold into imm offset:).
    for (int s = 0; s < n_super; ++s) {
        const int base = (s * GW + gw) * 256 + lane;
        float4v x0 = xv4[base];        int4v i0 = iv4[base];
        float4v x1 = xv4[base +  64];  int4v i1 = iv4[base +  64];
        float4v x2 = xv4[base + 128];  int4v i2 = iv4[base + 128];
        float4v x3 = xv4[base + 192];  int4v i3 = iv4[base + 192];
        __builtin_amdgcn_sched_barrier(0);  // keep all 8 loads issued first
        acc0 += bce4(x0, i0, mid, t);
        acc1 += bce4(x1, i1, mid, t);
        acc2 += bce4(x2, i2, mid, t);
        acc3 += bce4(x3, i3, mid, t);
    }

    // leftover float4s (when n_vec doesn't divide by GW*256)
    const int tid = blockIdx.x * blockDim.x + threadIdx.x;
    for (int i = n_super * GW * 256 + tid; i < n_vec; i += GW * 64)
        acc0 += bce4(xv4[i], iv4[i], mid, t);

    float acc = (acc0 + acc1) + (acc2 + acc3);

    // scalar tail (N not divisible by 4) — global thread 0 only
    if (tid == 0) {
        for (int k = n_vec * 4; k < n_total; ++k) {
            float xx = x[k];
            float w  = (idx[k] >= mid) ? 2.0f : 1.0f;
            float a  = fabsf(xx);
            acc += w * (fmaxf(xx, 0.0f) - xx * t + __logf(1.0f + __expf(-a)));
        }
    }

    // wave-64 butterfly reduce
    #pragma unroll
    for (int off = 32; off > 0; off >>= 1)
        acc += __shfl_down(acc, off, 64);

    __shared__ float smem[4];
    if (lane == 0) smem[wid] = acc;
    __syncthreads();
    if (threadIdx.x == 0)
        partials[blockIdx.x] = smem[0] + smem[1] + smem[2] + smem[3];
}

__global__ __launch_bounds__(256) void rwl_final_kernel(
        const float* __restrict__ partials, int n, float inv_total,
        float* __restrict__ out)
{
    float acc = 0.0f;
    for (int i = threadIdx.x; i < n; i += 256) acc += partials[i];
    #pragma unroll
    for (int off = 32; off > 0; off >>= 1)
        acc += __shfl_down(acc, off, 64);
    __shared__ float smem[4];
    const int lane = threadIdx.x & 63;
    const int wid  = threadIdx.x >> 6;
    if (lane == 0) smem[wid] = acc;
    __syncthreads();
    if (threadIdx.x == 0)
        out[0] = (smem[0] + smem[1] + smem[2] + smem[3]) * inv_total;
}

extern "C" void kernel_launch(void* const* d_in, const int* in_sizes, int n_in,
                              void* d_out, int out_size, void* d_ws, size_t ws_size,
                              hipStream_t stream) {
    const float* x      = (const float*)d_in[0];
    const void*  target = d_in[1];
    const int*   idx    = (const int*)d_in[2];
    const void*  Hp     = d_in[3];
    float* out          = (float*)d_out;
    float* partials     = (float*)d_ws;

    const int n_total = in_sizes[0];
    const int n_vec   = n_total >> 2;

    int blocks = (n_vec + 1023) / 1024;
    if (blocks > 2048) blocks = 2048;
    if (blocks < 1)    blocks = 1;

    const int GW      = blocks * 4;            // waves in grid
    const int chunk   = GW * 256;              // float4s per superstep
    const int n_super = n_vec / chunk;         // full supersteps (leftover looped)

    rwl_partial_kernel<<<blocks, 256, 0, stream>>>(
        x, idx, target, Hp, partials, n_vec, n_total, n_super);

    const float inv_total = 1.0f / (float)n_total;
    rwl_final_kernel<<<1, 256, 0, stream>>>(partials, blocks, inv_total, out);
}